// Round 5
// baseline (96.794 us; speedup 1.0000x reference)
//
#include <hip/hip_runtime.h>
#include <math.h>

#define N_RAYS 262144
#define N_SPHERES 256

// Module-scope staging buffer: avoids any assumption about ws_size, and the
// uniform-index reads in the main loop become s_load_dwordx4/x16 on the
// scalar pipe (separate issue port + constant cache -> frees VALU/LDS).
__device__ float4 g_sph[N_SPHERES];  // x,y,z = center, w = |c|^2 - r^2

__global__ __launch_bounds__(256) void setup_spheres(
    const float* __restrict__ sc, const float* __restrict__ sr)
{
    const int j = threadIdx.x;
    const float cx = sc[3 * j + 0];
    const float cy = sc[3 * j + 1];
    const float cz = sc[3 * j + 2];
    const float r  = sr[j];
    g_sph[j] = make_float4(cx, cy, cz,
                           fmaf(cz, cz, fmaf(cy, cy, cx * cx)) - r * r);
}

__global__ __launch_bounds__(256) void ray_sphere_kernel(
    const float* __restrict__ ro,   // (N,3)
    const float* __restrict__ rd,   // (N,3)
    float* __restrict__ out)        // 8N floats: t_hit | idx | hit_points | hit_normals
{
    const int i = blockIdx.x * blockDim.x + threadIdx.x;

    const float ox = ro[3 * i + 0], oy = ro[3 * i + 1], oz = ro[3 * i + 2];
    const float dx = rd[3 * i + 0], dy = rd[3 * i + 1], dz = rd[3 * i + 2];

    const float a       = fmaf(dz, dz, fmaf(dy, dy, dx * dx));
    const float d_dot_o = fmaf(dz, oz, fmaf(dy, oy, dx * ox));
    const float o_norm2 = fmaf(oz, oz, fmaf(oy, oy, ox * ox));
    const float inva    = 1.0f / a;
    const float nd      = -d_dot_o;          // m = d.c - d.o  (== -b/2)
    const float px = -2.0f * ox, py = -2.0f * oy, pz = -2.0f * oz;

    // u-space min (u = a*t): monotone in t since a > 0.
    float best_u = INFINITY;
    int   best_j = 0;  // argmin of all-inf row is 0 (matches jnp.argmin)

    // NOTE: inner-loop arithmetic kept bit-identical to the round-3 passing
    // kernel (disc via c-chain with o_norm2+s.w inside) — a reformulated
    // disc flipped a grazing hit in round 4 (absmax 160).
    #pragma unroll 4
    for (int j = 0; j < N_SPHERES; ++j) {
        const float4 s = g_sph[j];           // uniform -> scalar load
        const float m    = fmaf(dz, s.z, fmaf(dy, s.y, fmaf(dx, s.x, nd)));
        const float c    = fmaf(pz, s.z, fmaf(py, s.y, fmaf(px, s.x, o_norm2 + s.w)));
        const float disc = fmaf(m, m, -(a * c));           // (b^2-4ac)/4
        // Wave-uniform skip: ~90% of (wave, sphere) pairs have no lane with
        // a real root.
        if (__ballot(disc >= 0.0f) != 0ull) {
            // disc<0 lanes: sq=NaN -> u=NaN -> compares false -> no update.
            const float sq = __builtin_amdgcn_sqrtf(disc);
            const float u1 = m - sq;
            const float u2 = m + sq;
            const float u  = (u1 > 0.0f) ? u1 : u2;
            if (u > 0.0f && u < best_u) { best_u = u; best_j = j; }
        }
    }

    const float best_t = best_u * inva;
    const bool any_hit = isfinite(best_t);

    const float hx = fmaf(best_t, dx, ox);
    const float hy = fmaf(best_t, dy, oy);
    const float hz = fmaf(best_t, dz, oz);

    // One-time per-lane gather of the winning center (4 KB, L1-resident).
    const float4 cs = g_sph[any_hit ? best_j : 0];
    float nx = hx - cs.x, ny = hy - cs.y, nz = hz - cs.z;
    const float inv_nrm = __builtin_amdgcn_rsqf(fmaf(nz, nz, fmaf(ny, ny, nx * nx)));
    nx *= inv_nrm; ny *= inv_nrm; nz *= inv_nrm;
    if (!any_hit) { nx = 0.0f; ny = 0.0f; nz = 0.0f; }

    // outputs: t_hit [0,N) | sphere_idx [N,2N) | hit_points [2N,5N) | normals [5N,8N)
    out[i]            = best_t;
    out[N_RAYS + i]   = any_hit ? (float)best_j : -1.0f;
    float* hp = out + 2 * N_RAYS;
    hp[3 * i + 0] = hx; hp[3 * i + 1] = hy; hp[3 * i + 2] = hz;
    float* hn = out + 5 * N_RAYS;
    hn[3 * i + 0] = nx; hn[3 * i + 1] = ny; hn[3 * i + 2] = nz;
}

extern "C" void kernel_launch(void* const* d_in, const int* in_sizes, int n_in,
                              void* d_out, int out_size, void* d_ws, size_t ws_size,
                              hipStream_t stream) {
    const float* ro = (const float*)d_in[0];
    const float* rd = (const float*)d_in[1];
    const float* sc = (const float*)d_in[2];
    const float* sr = (const float*)d_in[3];
    float* out = (float*)d_out;

    setup_spheres<<<1, N_SPHERES, 0, stream>>>(sc, sr);
    ray_sphere_kernel<<<N_RAYS / 256, 256, 0, stream>>>(ro, rd, out);
}

// Round 6
// 92.406 us; speedup vs baseline: 1.0475x; 1.0475x over previous
//
#include <hip/hip_runtime.h>
#include <math.h>

#define N_RAYS 262144
#define N_SPHERES 256
// Each block handles 512 consecutive rays: thread t owns rays base+t and
// base+256+t (both halves coalesced). 2 rays/thread halves loop/branch/LDS
// overhead per ray and doubles ILP; grid = 512 blocks = 2 blocks/CU.

__global__ __launch_bounds__(256) void ray_sphere_kernel(
    const float* __restrict__ ro,   // (N,3)
    const float* __restrict__ rd,   // (N,3)
    const float* __restrict__ sc,   // (M,3)
    const float* __restrict__ sr,   // (M,)
    float* __restrict__ out)        // 8N floats: t_hit | idx | hit_points | hit_normals
{
    __shared__ float4 sph[N_SPHERES];  // x,y,z = center, w = |c|^2 - r^2

    const int tid = threadIdx.x;
    {
        const float cx = sc[3 * tid + 0];
        const float cy = sc[3 * tid + 1];
        const float cz = sc[3 * tid + 2];
        const float r  = sr[tid];
        sph[tid] = make_float4(cx, cy, cz,
                               fmaf(cz, cz, fmaf(cy, cy, cx * cx)) - r * r);
    }
    __syncthreads();

    const int iA = blockIdx.x * 512 + tid;
    const int iB = iA + 256;

    const float oxA = ro[3*iA+0], oyA = ro[3*iA+1], ozA = ro[3*iA+2];
    const float dxA = rd[3*iA+0], dyA = rd[3*iA+1], dzA = rd[3*iA+2];
    const float oxB = ro[3*iB+0], oyB = ro[3*iB+1], ozB = ro[3*iB+2];
    const float dxB = rd[3*iB+0], dyB = rd[3*iB+1], dzB = rd[3*iB+2];

    const float aA   = fmaf(dzA, dzA, fmaf(dyA, dyA, dxA * dxA));
    const float ndA  = -fmaf(dzA, ozA, fmaf(dyA, oyA, dxA * oxA));
    const float on2A = fmaf(ozA, ozA, fmaf(oyA, oyA, oxA * oxA));
    const float invaA = 1.0f / aA;
    const float pxA = -2.0f * oxA, pyA = -2.0f * oyA, pzA = -2.0f * ozA;

    const float aB   = fmaf(dzB, dzB, fmaf(dyB, dyB, dxB * dxB));
    const float ndB  = -fmaf(dzB, ozB, fmaf(dyB, oyB, dxB * oxB));
    const float on2B = fmaf(ozB, ozB, fmaf(oyB, oyB, oxB * oxB));
    const float invaB = 1.0f / aB;
    const float pxB = -2.0f * oxB, pyB = -2.0f * oyB, pzB = -2.0f * ozB;

    // u-space min (u = a*t): monotone in t since a > 0.
    float bestuA = INFINITY; int bestjA = 0;
    float bestuB = INFINITY; int bestjB = 0;

    // Inner-loop arithmetic bit-identical to the round-3 passing kernel
    // (disc reformulation flipped a grazing hit in round 4 — don't touch).
    #pragma unroll 4
    for (int j = 0; j < N_SPHERES; ++j) {
        const float4 s = sph[j];             // uniform index -> LDS broadcast
        const float mA    = fmaf(dzA, s.z, fmaf(dyA, s.y, fmaf(dxA, s.x, ndA)));
        const float cA    = fmaf(pzA, s.z, fmaf(pyA, s.y, fmaf(pxA, s.x, on2A + s.w)));
        const float discA = fmaf(mA, mA, -(aA * cA));
        const float mB    = fmaf(dzB, s.z, fmaf(dyB, s.y, fmaf(dxB, s.x, ndB)));
        const float cB    = fmaf(pzB, s.z, fmaf(pyB, s.y, fmaf(pxB, s.x, on2B + s.w)));
        const float discB = fmaf(mB, mB, -(aB * cB));
        // Wave-uniform skip over 128 rays' worth of work (~88% skipped).
        if (__ballot((discA >= 0.0f) || (discB >= 0.0f)) != 0ull) {
            // disc<0 lanes: sq=NaN -> u=NaN -> compares false -> no update.
            {
                const float sq = __builtin_amdgcn_sqrtf(discA);
                const float u1 = mA - sq, u2 = mA + sq;
                const float u  = (u1 > 0.0f) ? u1 : u2;
                if (u > 0.0f && u < bestuA) { bestuA = u; bestjA = j; }
            }
            {
                const float sq = __builtin_amdgcn_sqrtf(discB);
                const float u1 = mB - sq, u2 = mB + sq;
                const float u  = (u1 > 0.0f) ? u1 : u2;
                if (u > 0.0f && u < bestuB) { bestuB = u; bestjB = j; }
            }
        }
    }

    float* hp = out + 2 * N_RAYS;
    float* hn = out + 5 * N_RAYS;

    // Epilogue for both rays.
    {
        const float best_t = bestuA * invaA;
        const bool any_hit = isfinite(best_t);
        const float hx = fmaf(best_t, dxA, oxA);
        const float hy = fmaf(best_t, dyA, oyA);
        const float hz = fmaf(best_t, dzA, ozA);
        const float4 cs = sph[any_hit ? bestjA : 0];
        float nx = hx - cs.x, ny = hy - cs.y, nz = hz - cs.z;
        const float inv_nrm = __builtin_amdgcn_rsqf(fmaf(nz, nz, fmaf(ny, ny, nx * nx)));
        nx *= inv_nrm; ny *= inv_nrm; nz *= inv_nrm;
        if (!any_hit) { nx = 0.0f; ny = 0.0f; nz = 0.0f; }
        out[iA]          = best_t;
        out[N_RAYS + iA] = any_hit ? (float)bestjA : -1.0f;
        hp[3*iA+0] = hx; hp[3*iA+1] = hy; hp[3*iA+2] = hz;
        hn[3*iA+0] = nx; hn[3*iA+1] = ny; hn[3*iA+2] = nz;
    }
    {
        const float best_t = bestuB * invaB;
        const bool any_hit = isfinite(best_t);
        const float hx = fmaf(best_t, dxB, oxB);
        const float hy = fmaf(best_t, dyB, oyB);
        const float hz = fmaf(best_t, dzB, ozB);
        const float4 cs = sph[any_hit ? bestjB : 0];
        float nx = hx - cs.x, ny = hy - cs.y, nz = hz - cs.z;
        const float inv_nrm = __builtin_amdgcn_rsqf(fmaf(nz, nz, fmaf(ny, ny, nx * nx)));
        nx *= inv_nrm; ny *= inv_nrm; nz *= inv_nrm;
        if (!any_hit) { nx = 0.0f; ny = 0.0f; nz = 0.0f; }
        out[iB]          = best_t;
        out[N_RAYS + iB] = any_hit ? (float)bestjB : -1.0f;
        hp[3*iB+0] = hx; hp[3*iB+1] = hy; hp[3*iB+2] = hz;
        hn[3*iB+0] = nx; hn[3*iB+1] = ny; hn[3*iB+2] = nz;
    }
}

extern "C" void kernel_launch(void* const* d_in, const int* in_sizes, int n_in,
                              void* d_out, int out_size, void* d_ws, size_t ws_size,
                              hipStream_t stream) {
    const float* ro = (const float*)d_in[0];
    const float* rd = (const float*)d_in[1];
    const float* sc = (const float*)d_in[2];
    const float* sr = (const float*)d_in[3];
    float* out = (float*)d_out;

    ray_sphere_kernel<<<N_RAYS / 512, 256, 0, stream>>>(ro, rd, sc, sr, out);
}

// Round 7
// 91.811 us; speedup vs baseline: 1.0543x; 1.0065x over previous
//
#include <hip/hip_runtime.h>
#include <math.h>

#define N_RAYS 262144
#define N_SPHERES 256

__global__ __launch_bounds__(256) void ray_sphere_kernel(
    const float* __restrict__ ro,   // (N,3)
    const float* __restrict__ rd,   // (N,3)
    const float* __restrict__ sc,   // (M,3)
    const float* __restrict__ sr,   // (M,)
    float* __restrict__ out)        // 8N floats: t_hit | idx | hit_points | hit_normals
{
    __shared__ float4 sph[N_SPHERES];  // x,y,z = center, w = |c|^2 - r^2

    const int tid = threadIdx.x;
    {
        const float cx = sc[3 * tid + 0];
        const float cy = sc[3 * tid + 1];
        const float cz = sc[3 * tid + 2];
        const float r  = sr[tid];
        sph[tid] = make_float4(cx, cy, cz,
                               fmaf(cz, cz, fmaf(cy, cy, cx * cx)) - r * r);
    }
    __syncthreads();

    const int i = blockIdx.x * blockDim.x + tid;

    const float ox = ro[3 * i + 0], oy = ro[3 * i + 1], oz = ro[3 * i + 2];
    const float dx = rd[3 * i + 0], dy = rd[3 * i + 1], dz = rd[3 * i + 2];

    const float a    = fmaf(dz, dz, fmaf(dy, dy, dx * dx));
    const float nd   = -fmaf(dz, oz, fmaf(dy, oy, dx * ox));   // m = d.c - d.o
    const float on2  = fmaf(oz, oz, fmaf(oy, oy, ox * ox));
    const float inva = 1.0f / a;
    const float px = -2.0f * ox, py = -2.0f * oy, pz = -2.0f * oz;

    // u-space min (u = a*t): monotone in t since a > 0.
    float best_u = INFINITY;
    int   best_j = 0;  // argmin of all-inf row is 0 (matches jnp.argmin)

    // Software-pipelined, group-of-4 loop:
    //  - next group's 4 float4s are loaded at the TOP of each iteration so
    //    LDS latency overlaps this group's disc computation (rolled loop,
    //    unroll 1, keeps the pipeline structure).
    //  - ONE ballot per 4 spheres amortizes the v_cmp->s_cbranch bubble.
    //  - per-sphere math bit-identical to the round-3 passing kernel.
    float4 s0 = sph[0], s1 = sph[1], s2 = sph[2], s3 = sph[3];

    #pragma unroll 1
    for (int j = 0; j < N_SPHERES; j += 4) {
        const float4 c0 = s0, c1 = s1, c2 = s2, c3 = s3;
        const int jn = (j + 4) & (N_SPHERES - 1);   // wrap: last prefetch harmless
        s0 = sph[jn + 0]; s1 = sph[jn + 1]; s2 = sph[jn + 2]; s3 = sph[jn + 3];

        const float m0 = fmaf(dz, c0.z, fmaf(dy, c0.y, fmaf(dx, c0.x, nd)));
        const float q0 = fmaf(pz, c0.z, fmaf(py, c0.y, fmaf(px, c0.x, on2 + c0.w)));
        const float d0 = fmaf(m0, m0, -(a * q0));
        const float m1 = fmaf(dz, c1.z, fmaf(dy, c1.y, fmaf(dx, c1.x, nd)));
        const float q1 = fmaf(pz, c1.z, fmaf(py, c1.y, fmaf(px, c1.x, on2 + c1.w)));
        const float d1 = fmaf(m1, m1, -(a * q1));
        const float m2 = fmaf(dz, c2.z, fmaf(dy, c2.y, fmaf(dx, c2.x, nd)));
        const float q2 = fmaf(pz, c2.z, fmaf(py, c2.y, fmaf(px, c2.x, on2 + c2.w)));
        const float d2 = fmaf(m2, m2, -(a * q2));
        const float m3 = fmaf(dz, c3.z, fmaf(dy, c3.y, fmaf(dx, c3.x, nd)));
        const float q3 = fmaf(pz, c3.z, fmaf(py, c3.y, fmaf(px, c3.x, on2 + c3.w)));
        const float d3 = fmaf(m3, m3, -(a * q3));

        // any lane, any of 4 spheres with a real root? (inputs finite -> no NaN)
        const float dmax = fmaxf(fmaxf(d0, d1), fmaxf(d2, d3));
        if (__ballot(dmax >= 0.0f) != 0ull) {
            // disc<0 lanes: sq=NaN -> u=NaN -> compares false -> no update.
            {
                const float sq = __builtin_amdgcn_sqrtf(d0);
                const float u1 = m0 - sq, u2 = m0 + sq;
                const float u  = (u1 > 0.0f) ? u1 : u2;
                if (u > 0.0f && u < best_u) { best_u = u; best_j = j + 0; }
            }
            {
                const float sq = __builtin_amdgcn_sqrtf(d1);
                const float u1 = m1 - sq, u2 = m1 + sq;
                const float u  = (u1 > 0.0f) ? u1 : u2;
                if (u > 0.0f && u < best_u) { best_u = u; best_j = j + 1; }
            }
            {
                const float sq = __builtin_amdgcn_sqrtf(d2);
                const float u1 = m2 - sq, u2 = m2 + sq;
                const float u  = (u1 > 0.0f) ? u1 : u2;
                if (u > 0.0f && u < best_u) { best_u = u; best_j = j + 2; }
            }
            {
                const float sq = __builtin_amdgcn_sqrtf(d3);
                const float u1 = m3 - sq, u2 = m3 + sq;
                const float u  = (u1 > 0.0f) ? u1 : u2;
                if (u > 0.0f && u < best_u) { best_u = u; best_j = j + 3; }
            }
        }
    }

    const float best_t = best_u * inva;
    const bool any_hit = isfinite(best_t);

    const float hx = fmaf(best_t, dx, ox);
    const float hy = fmaf(best_t, dy, oy);
    const float hz = fmaf(best_t, dz, oz);

    const float4 cs = sph[any_hit ? best_j : 0];
    float nx = hx - cs.x, ny = hy - cs.y, nz = hz - cs.z;
    const float inv_nrm = __builtin_amdgcn_rsqf(fmaf(nz, nz, fmaf(ny, ny, nx * nx)));
    nx *= inv_nrm; ny *= inv_nrm; nz *= inv_nrm;
    if (!any_hit) { nx = 0.0f; ny = 0.0f; nz = 0.0f; }

    // outputs: t_hit [0,N) | sphere_idx [N,2N) | hit_points [2N,5N) | normals [5N,8N)
    out[i]            = best_t;
    out[N_RAYS + i]   = any_hit ? (float)best_j : -1.0f;
    float* hp = out + 2 * N_RAYS;
    hp[3 * i + 0] = hx; hp[3 * i + 1] = hy; hp[3 * i + 2] = hz;
    float* hn = out + 5 * N_RAYS;
    hn[3 * i + 0] = nx; hn[3 * i + 1] = ny; hn[3 * i + 2] = nz;
}

extern "C" void kernel_launch(void* const* d_in, const int* in_sizes, int n_in,
                              void* d_out, int out_size, void* d_ws, size_t ws_size,
                              hipStream_t stream) {
    const float* ro = (const float*)d_in[0];
    const float* rd = (const float*)d_in[1];
    const float* sc = (const float*)d_in[2];
    const float* sr = (const float*)d_in[3];
    float* out = (float*)d_out;

    ray_sphere_kernel<<<N_RAYS / 256, 256, 0, stream>>>(ro, rd, sc, sr, out);
}